// Round 12
// baseline (283.820 us; speedup 1.0000x reference)
//
#include <hip/hip_runtime.h>
#include <stdint.h>

typedef __attribute__((ext_vector_type(8))) _Float16 half8v;
typedef __attribute__((ext_vector_type(4))) float float4v;

#define NPTS_WG 16

// u16-plane index for A[c][p][k]: row = 256 u16 = 32 8-elem granules; granule ^= p.
__device__ __forceinline__ int aidx16(int c, int p, int k) {
    return ((c * 16 + p) << 8) + ((((k >> 3) ^ p) << 3) | (k & 7));
}

__device__ __forceinline__ unsigned short f16b(float x) {
    const _Float16 h = (_Float16)x;            // RN, 11-bit mantissa
    return __builtin_bit_cast(unsigned short, h);
}

__device__ __forceinline__ uint32_t pk2f16(float a, float b) {
    return (uint32_t)f16b(a) | ((uint32_t)f16b(b) << 16);
}

__device__ __forceinline__ float fast_tanh(float z) {
    const float e = __expf(2.0f * z);          // ~2 ulp
    return 1.0f - 2.0f / (e + 1.0f);           // exact saturation
}

// ---- precompute: transpose + f16 hi/lo split W1..W3 into d_ws ----
// wt layout: [L][{hi,lo}][j][k] ushort(f16 bits); hi at L*131072 + j*256 + k, lo +65536
__global__ void wt_split_kernel(const float* __restrict__ W1, const float* __restrict__ W2,
                                const float* __restrict__ W3, unsigned short* __restrict__ wt)
{
    const int b = blockIdx.x;            // 48 blocks: 3 layers x 16 k-strips
    const int L = b >> 4;
    const int k0 = (b & 15) * 16;
    const float* W = (L == 0) ? W1 : (L == 1) ? W2 : W3;
    const int j = threadIdx.x;           // 0..255
    uint32_t hi[16], lo[16];
#pragma unroll
    for (int e = 0; e < 16; ++e) {
        const float x = W[(k0 + e) * 256 + j];     // coalesced: lanes = consecutive j
        const unsigned short h = f16b(x);
        const float hf = (float)__builtin_bit_cast(_Float16, h);
        hi[e] = h;
        lo[e] = f16b(x - hf);
    }
    unsigned short* dh = wt + (size_t)L * 131072 + j * 256 + k0;
    unsigned short* dl = dh + 65536;
    uint4 h0 = make_uint4(hi[0] | (hi[1] << 16), hi[2] | (hi[3] << 16),
                          hi[4] | (hi[5] << 16), hi[6] | (hi[7] << 16));
    uint4 h1 = make_uint4(hi[8] | (hi[9] << 16), hi[10] | (hi[11] << 16),
                          hi[12] | (hi[13] << 16), hi[14] | (hi[15] << 16));
    uint4 l0 = make_uint4(lo[0] | (lo[1] << 16), lo[2] | (lo[3] << 16),
                          lo[4] | (lo[5] << 16), lo[6] | (lo[7] << 16));
    uint4 l1 = make_uint4(lo[8] | (lo[9] << 16), lo[10] | (lo[11] << 16),
                          lo[12] | (lo[13] << 16), lo[14] | (lo[15] << 16));
    ((uint4*)dh)[0] = h0; ((uint4*)dh)[1] = h1;
    ((uint4*)dl)[0] = l0; ((uint4*)dl)[1] = l1;
}

// ---- main kernel: 512 threads (8 waves x 2 j-tiles), 16 pts/WG ----
// launch_bounds(512,2): 1 WG/CU, 2 waves/SIMD, 256 unified regs/wave.
// Layer-resident B (128 regs) + per-channel A batch (32) + acc (56) = ~230.
__global__ __launch_bounds__(512, 2)
void pinn_mfma(const float* __restrict__ x_norm, const float* __restrict__ nu,
               const float* __restrict__ x_std, const float* __restrict__ y_std,
               const float* __restrict__ W0, const float* __restrict__ b0,
               const float* __restrict__ b1, const float* __restrict__ b2,
               const float* __restrict__ b3, const float* __restrict__ W4,
               const unsigned short* __restrict__ wt, float* __restrict__ out)
{
    __shared__ unsigned short AH[7 * 16 * 256]; // 57344 B f16 activations (fragment order)
    __shared__ float w4_lds[256 * 4];           // 4 KB
    __shared__ float part_lds[8 * 6 * 16 * 4];  // 12 KB split-K partials
    __shared__ float y_lds[24 * 16];            // 1.5 KB

    const int tid = threadIdx.x;
    const int lane = tid & 63;
    const int wv = tid >> 6;     // wave 0..7
    const int l15 = lane & 15;
    const int g = lane >> 4;     // 0..3
    const int base_pt = blockIdx.x * NPTS_WG;

    if (tid < 256) ((float4*)w4_lds)[tid] = ((const float4*)W4)[tid];

    // ---- layer 0: 3 -> 256 dual seed ----
    {
        const int p = tid >> 5;            // 0..15
        const int j8 = (tid & 31) * 8;
        const float x0 = x_norm[(base_pt + p) * 3 + 0];
        const float x1 = x_norm[(base_pt + p) * 3 + 1];
        const float x2 = x_norm[(base_pt + p) * 3 + 2];
        float w0r[8], w1r[8], w2r[8], b0r[8];
        *(float4*)&w0r[0] = *(const float4*)&W0[0 * 256 + j8];
        *(float4*)&w0r[4] = *(const float4*)&W0[0 * 256 + j8 + 4];
        *(float4*)&w1r[0] = *(const float4*)&W0[1 * 256 + j8];
        *(float4*)&w1r[4] = *(const float4*)&W0[1 * 256 + j8 + 4];
        *(float4*)&w2r[0] = *(const float4*)&W0[2 * 256 + j8];
        *(float4*)&w2r[4] = *(const float4*)&W0[2 * 256 + j8 + 4];
        *(float4*)&b0r[0] = *(const float4*)&b0[j8];
        *(float4*)&b0r[4] = *(const float4*)&b0[j8 + 4];
        union { unsigned short u[8]; half8v v; } hv[7];
#pragma unroll
        for (int e = 0; e < 8; ++e) {
            const float z = b0r[e] + x0 * w0r[e] + x1 * w1r[e] + x2 * w2r[e];
            const float t = fast_tanh(z);
            const float s = 1.f - t * t;
            hv[0].u[e] = f16b(t);
            const float wvv[3] = {w0r[e], w1r[e], w2r[e]};
#pragma unroll
            for (int i = 0; i < 3; ++i) {
                hv[1 + i].u[e] = f16b(s * wvv[i]);
                hv[4 + i].u[e] = f16b(-2.f * t * s * wvv[i] * wvv[i]);
            }
        }
#pragma unroll
        for (int c = 0; c < 7; ++c)
            *(half8v*)&AH[aidx16(c, p, j8)] = hv[c].v;  // j8 8-aligned: one granule
    }
    __syncthreads();

    // ---- layers 1..3: layer-resident B, per-channel batched A, clean MFMA ----
    const float* biases[3] = {b1, b2, b3};
    const int jrow0 = (wv * 32 + l15) * 256;        // jt=0 row base
    const int jrow1 = (wv * 32 + 16 + l15) * 256;   // jt=1 row base
    const int k0 = 8 * g;

    // B register file for one full layer: 2 jt x 8 ks x {hi,lo} = 128 regs
    half8v BH0[8], BH1[8], BL0[8], BL1[8];
#pragma unroll
    for (int ks = 0; ks < 8; ++ks) {
        const int k = ks * 32 + k0;
        BH0[ks] = *(const half8v*)(wt + jrow0 + k);
        BH1[ks] = *(const half8v*)(wt + jrow1 + k);
        BL0[ks] = *(const half8v*)(wt + 65536 + jrow0 + k);
        BL1[ks] = *(const half8v*)(wt + 65536 + jrow1 + k);
    }

#pragma unroll 1
    for (int L = 0; L < 3; ++L) {
        float4v acc[7][2];
#pragma unroll
        for (int c = 0; c < 7; ++c)
#pragma unroll
            for (int jt = 0; jt < 2; ++jt) acc[c][jt] = (float4v){0.f, 0.f, 0.f, 0.f};

#pragma unroll
        for (int c = 0; c < 7; ++c) {
            // batch-read all 8 A granules of this channel (32 regs, one wait)
            half8v a[8];
#pragma unroll
            for (int ks = 0; ks < 8; ++ks)
                a[ks] = *(const half8v*)&AH[aidx16(c, l15, ks * 32 + k0)];
            __builtin_amdgcn_s_setprio(1);
            // register-resident MFMA block: two independent acc chains (jt0/jt1)
#pragma unroll
            for (int ks = 0; ks < 8; ++ks) {
                acc[c][0] = __builtin_amdgcn_mfma_f32_16x16x32_f16(BH0[ks], a[ks], acc[c][0], 0, 0, 0);
                acc[c][1] = __builtin_amdgcn_mfma_f32_16x16x32_f16(BH1[ks], a[ks], acc[c][1], 0, 0, 0);
            }
            if (c < 4) {   // d2 channels (4..6): hi-product only (nu-damped 100x)
#pragma unroll
                for (int ks = 0; ks < 8; ++ks) {
                    acc[c][0] = __builtin_amdgcn_mfma_f32_16x16x32_f16(BL0[ks], a[ks], acc[c][0], 0, 0, 0);
                    acc[c][1] = __builtin_amdgcn_mfma_f32_16x16x32_f16(BL1[ks], a[ks], acc[c][1], 0, 0, 0);
                }
            }
            __builtin_amdgcn_s_setprio(0);
        }

        // B regs now dead: issue next layer's B loads, in flight across transform
        if (L < 2) {
            const unsigned short* wtN = wt + (size_t)(L + 1) * 131072;
#pragma unroll
            for (int ks = 0; ks < 8; ++ks) {
                const int k = ks * 32 + k0;
                BH0[ks] = *(const half8v*)(wtN + jrow0 + k);
                BH1[ks] = *(const half8v*)(wtN + jrow1 + k);
                BL0[ks] = *(const half8v*)(wtN + 65536 + jrow0 + k);
                BL1[ks] = *(const half8v*)(wtN + 65536 + jrow1 + k);
            }
        }

        const float* bL = biases[L];
        float bj[2][4];
        *(float4*)&bj[0][0] = *(const float4*)&bL[wv * 32 + 4 * g];
        *(float4*)&bj[1][0] = *(const float4*)&bL[wv * 32 + 16 + 4 * g];
        __syncthreads();   // all reads of A done before overwrite
#pragma unroll
        for (int jt = 0; jt < 2; ++jt) {
            const int jb = wv * 32 + jt * 16 + 4 * g;   // 4-aligned j-run base
            float val[7][4];
#pragma unroll
            for (int r = 0; r < 4; ++r) {
                const float z = acc[0][jt][r] + bj[jt][r];
                const float t = fast_tanh(z);
                const float s = 1.f - t * t;
                val[0][r] = t;
#pragma unroll
                for (int i = 0; i < 3; ++i) {
                    const float d1 = acc[1 + i][jt][r];
                    const float d2 = acc[4 + i][jt][r];
                    val[1 + i][r] = s * d1;
                    val[4 + i][r] = s * d2 - 2.f * t * s * d1 * d1;
                }
            }
            const int gr = jb >> 3, off = jb & 7;
#pragma unroll
            for (int c = 0; c < 7; ++c) {
                const uint32_t u0 = pk2f16(val[c][0], val[c][1]);
                const uint32_t u1 = pk2f16(val[c][2], val[c][3]);
                *(uint2*)&AH[((c * 16 + l15) << 8) + ((gr ^ l15) << 3) + off] =
                    make_uint2(u0, u1);   // one ds_write_b64, 8B-aligned
            }
        }
        __syncthreads();
    }

    // ---- layer 4: 256 -> 4, split-K across 8 waves (32 k each), swapped ----
    {
        const int koct = wv * 32 + 8 * g;
        union { uint32_t u[4]; half8v v; } HB, LB;
#pragma unroll
        for (int i = 0; i < 4; ++i) {
            const float w0v = (l15 < 4) ? w4_lds[(koct + 2 * i) * 4 + l15] : 0.f;
            const float w1v = (l15 < 4) ? w4_lds[(koct + 2 * i + 1) * 4 + l15] : 0.f;
            const unsigned short h0 = f16b(w0v), h1 = f16b(w1v);
            const float r0 = w0v - (float)__builtin_bit_cast(_Float16, h0);
            const float r1 = w1v - (float)__builtin_bit_cast(_Float16, h1);
            HB.u[i] = (uint32_t)h0 | ((uint32_t)h1 << 16);
            LB.u[i] = (uint32_t)f16b(r0) | ((uint32_t)f16b(r1) << 16);
        }
        float4v acc4[6];
#pragma unroll
        for (int c = 0; c < 6; ++c) acc4[c] = (float4v){0.f, 0.f, 0.f, 0.f};
#pragma unroll
        for (int c = 0; c < 6; ++c) {
            const half8v ah = *(const half8v*)&AH[aidx16(1 + c, l15, koct)];
            acc4[c] = __builtin_amdgcn_mfma_f32_16x16x32_f16(HB.v, ah, acc4[c], 0, 0, 0);
            if (c < 3)
                acc4[c] = __builtin_amdgcn_mfma_f32_16x16x32_f16(LB.v, ah, acc4[c], 0, 0, 0);
        }
        if (g == 0) {   // rows 0..3 = outputs u,v,w,p for point l15
#pragma unroll
            for (int c = 0; c < 6; ++c)
                *(float4*)&part_lds[((wv * 6 + c) * 16 + l15) * 4] =
                    make_float4(acc4[c][0], acc4[c][1], acc4[c][2], acc4[c][3]);
        }
    }
    __syncthreads();

    if (tid < 384) {          // reduce split-K partials + de-normalization scale
        const int p = tid & 15;
        const int co = tid >> 4;      // 0..23
        const int o = co & 3;
        const int c6 = co >> 2;       // 0..5: 0-2 = d1_i, 3-5 = d2_i
        float sum = 0.f;
#pragma unroll
        for (int w8 = 0; w8 < 8; ++w8) sum += part_lds[((w8 * 6 + c6) * 16 + p) * 4 + o];
        const int i = (c6 < 3) ? c6 : (c6 - 3);
        const float xs = x_std[i];
        const float scale = y_std[o] / ((c6 < 3) ? xs : (xs * xs));
        y_lds[co * 16 + p] = sum * scale;
    }
    __syncthreads();

    if (tid < 16) {           // physics loss per point
        const int p = tid;
        const float nuv = nu[0];
        #define YV(c6, o) y_lds[(((c6) * 4) + (o)) * 16 + p]
        const float cont = YV(0, 0) + YV(1, 1) + YV(2, 2);
        const float lap0 = YV(3, 0) + YV(4, 0) + YV(5, 0);
        const float lap1 = YV(3, 1) + YV(4, 1) + YV(5, 1);
        const float lap2 = YV(3, 2) + YV(4, 2) + YV(5, 2);
        const float mx = YV(0, 3) - nuv * lap0;
        const float my = YV(1, 3) - nuv * lap1;
        const float mz = YV(2, 3) - nuv * lap2;
        out[base_pt + p] = cont * cont + mx * mx + my * my + mz * mz;
        #undef YV
    }
}

extern "C" void kernel_launch(void* const* d_in, const int* in_sizes, int n_in,
                              void* d_out, int out_size, void* d_ws, size_t ws_size,
                              hipStream_t stream)
{
    const float* x_norm = (const float*)d_in[0];
    const float* nu     = (const float*)d_in[1];
    const float* x_std  = (const float*)d_in[2];
    const float* y_std  = (const float*)d_in[3];
    const float* W0 = (const float*)d_in[4];  const float* b0 = (const float*)d_in[5];
    const float* W1 = (const float*)d_in[6];  const float* b1 = (const float*)d_in[7];
    const float* W2 = (const float*)d_in[8];  const float* b2 = (const float*)d_in[9];
    const float* W3 = (const float*)d_in[10]; const float* b3 = (const float*)d_in[11];
    const float* W4 = (const float*)d_in[12];
    (void)n_in; (void)out_size; (void)ws_size;
    unsigned short* wt = (unsigned short*)d_ws;   // 786432 B
    float* out = (float*)d_out;
    const int npts = in_sizes[0] / 3;

    wt_split_kernel<<<48, 256, 0, stream>>>(W1, W2, W3, wt);
    pinn_mfma<<<npts / NPTS_WG, 512, 0, stream>>>(x_norm, nu, x_std, y_std,
        W0, b0, b1, b2, b3, W4, wt, out);
}

// Round 13
// 185.736 us; speedup vs baseline: 1.5281x; 1.5281x over previous
//
#include <hip/hip_runtime.h>
#include <stdint.h>

typedef __attribute__((ext_vector_type(8))) _Float16 half8v;
typedef __attribute__((ext_vector_type(16))) float float16v;
typedef __attribute__((ext_vector_type(4))) float float4v;

#define NPTS_WG 32

// LDS act plane: [c][p 32][j 256] u16. 16B granules (8 u16) swizzled g' = (j>>3) ^ p.
// Any 16B-granule access computes its own index.
__device__ __forceinline__ int aidx32(int c, int p, int j) {
    return ((c * 32 + p) << 8) + ((((j >> 3) ^ p) << 3) | (j & 7));
}

__device__ __forceinline__ unsigned short f16b(float x) {
    const _Float16 h = (_Float16)x;            // RN, 11-bit mantissa
    return __builtin_bit_cast(unsigned short, h);
}

__device__ __forceinline__ uint32_t pk2f16(float a, float b) {
    return (uint32_t)f16b(a) | ((uint32_t)f16b(b) << 16);
}

__device__ __forceinline__ float fast_tanh(float z) {
    const float e = __expf(2.0f * z);          // ~2 ulp
    return 1.0f - 2.0f / (e + 1.0f);           // exact saturation
}

// ---- precompute: transpose + f16 hi/lo split W1..W3 into d_ws ----
// wt layout: [L][{hi,lo}][j][k] ushort(f16 bits); hi at L*131072 + j*256 + k, lo +65536
__global__ void wt_split_kernel(const float* __restrict__ W1, const float* __restrict__ W2,
                                const float* __restrict__ W3, unsigned short* __restrict__ wt)
{
    const int b = blockIdx.x;            // 48 blocks: 3 layers x 16 k-strips
    const int L = b >> 4;
    const int k0 = (b & 15) * 16;
    const float* W = (L == 0) ? W1 : (L == 1) ? W2 : W3;
    const int j = threadIdx.x;           // 0..255
    uint32_t hi[16], lo[16];
#pragma unroll
    for (int e = 0; e < 16; ++e) {
        const float x = W[(k0 + e) * 256 + j];     // coalesced: lanes = consecutive j
        const unsigned short h = f16b(x);
        const float hf = (float)__builtin_bit_cast(_Float16, h);
        hi[e] = h;
        lo[e] = f16b(x - hf);
    }
    unsigned short* dh = wt + (size_t)L * 131072 + j * 256 + k0;
    unsigned short* dl = dh + 65536;
    uint4 h0 = make_uint4(hi[0] | (hi[1] << 16), hi[2] | (hi[3] << 16),
                          hi[4] | (hi[5] << 16), hi[6] | (hi[7] << 16));
    uint4 h1 = make_uint4(hi[8] | (hi[9] << 16), hi[10] | (hi[11] << 16),
                          hi[12] | (hi[13] << 16), hi[14] | (hi[15] << 16));
    uint4 l0 = make_uint4(lo[0] | (lo[1] << 16), lo[2] | (lo[3] << 16),
                          lo[4] | (lo[5] << 16), lo[6] | (lo[7] << 16));
    uint4 l1 = make_uint4(lo[8] | (lo[9] << 16), lo[10] | (lo[11] << 16),
                          lo[12] | (lo[13] << 16), lo[14] | (lo[15] << 16));
    ((uint4*)dh)[0] = h0; ((uint4*)dh)[1] = h1;
    ((uint4*)dl)[0] = l0; ((uint4*)dl)[1] = l1;
}

// ---- main kernel: 512 threads (8 waves), 32 points/WG, 32x32x16 MFMA ----
// launch_bounds(512,2): 1 WG/CU, 2 waves/SIMD, 256 unified regs/wave.
// acc 7x16 = 112 AGPR; W+A depth-1 dbuf ~72 VGPR; fits.
__global__ __launch_bounds__(512, 2)
void pinn_mfma(const float* __restrict__ x_norm, const float* __restrict__ nu,
               const float* __restrict__ x_std, const float* __restrict__ y_std,
               const float* __restrict__ W0, const float* __restrict__ b0,
               const float* __restrict__ b1, const float* __restrict__ b2,
               const float* __restrict__ b3, const float* __restrict__ W4,
               const unsigned short* __restrict__ wt, float* __restrict__ out)
{
    __shared__ unsigned short AH[7 * 32 * 256]; // 114688 B f16 activations
    __shared__ float w4_lds[256 * 4];           // 4 KB
    __shared__ float part_lds[8 * 6 * 32 * 4];  // 24 KB split-K partials
    __shared__ float y_lds[24 * 32];            // 3 KB

    const int tid = threadIdx.x;
    const int lane = tid & 63;
    const int wv = tid >> 6;     // wave 0..7
    const int l31 = lane & 31;
    const int hh = lane >> 5;    // 0..1 (k-half selector for 32x32 fragments)
    const int base_pt = blockIdx.x * NPTS_WG;

    if (tid < 256) ((float4*)w4_lds)[tid] = ((const float4*)W4)[tid];

    // ---- layer 0: 3 -> 256 dual seed (thread: 16 j units of 1 point) ----
    {
        const int p = tid >> 4;            // 0..31
        const int jq = tid & 15;
        const float x0 = x_norm[(base_pt + p) * 3 + 0];
        const float x1 = x_norm[(base_pt + p) * 3 + 1];
        const float x2 = x_norm[(base_pt + p) * 3 + 2];
#pragma unroll
        for (int hf = 0; hf < 2; ++hf) {
            const int j8 = jq * 16 + hf * 8;
            float w0r[8], w1r[8], w2r[8], b0r[8];
            *(float4*)&w0r[0] = *(const float4*)&W0[0 * 256 + j8];
            *(float4*)&w0r[4] = *(const float4*)&W0[0 * 256 + j8 + 4];
            *(float4*)&w1r[0] = *(const float4*)&W0[1 * 256 + j8];
            *(float4*)&w1r[4] = *(const float4*)&W0[1 * 256 + j8 + 4];
            *(float4*)&w2r[0] = *(const float4*)&W0[2 * 256 + j8];
            *(float4*)&w2r[4] = *(const float4*)&W0[2 * 256 + j8 + 4];
            *(float4*)&b0r[0] = *(const float4*)&b0[j8];
            *(float4*)&b0r[4] = *(const float4*)&b0[j8 + 4];
            union { unsigned short u[8]; half8v v; } hv[7];
#pragma unroll
            for (int e = 0; e < 8; ++e) {
                const float z = b0r[e] + x0 * w0r[e] + x1 * w1r[e] + x2 * w2r[e];
                const float t = fast_tanh(z);
                const float s = 1.f - t * t;
                hv[0].u[e] = f16b(t);
                const float wvv[3] = {w0r[e], w1r[e], w2r[e]};
#pragma unroll
                for (int i = 0; i < 3; ++i) {
                    hv[1 + i].u[e] = f16b(s * wvv[i]);
                    hv[4 + i].u[e] = f16b(-2.f * t * s * wvv[i] * wvv[i]);
                }
            }
#pragma unroll
            for (int c = 0; c < 7; ++c)
                *(half8v*)&AH[aidx32(c, p, j8)] = hv[c].v;  // one 16B granule
        }
    }
    __syncthreads();

    // ---- layers 1..3: D[j' 32][p 32] = W x A via mfma_32x32x16 ----
    // A-op (W): lane row j' = jb + l31, k = chunk*16 + 8*hh + e  (wt row-major)
    // B-op (act): lane col p = l31, k(j) = chunk*16 + 8*hh + e   (LDS plane)
    const float* biases[3] = {b1, b2, b3};
    const int jrow = (wv * 32 + l31) * 256;
    const int kofs = 8 * hh;

#pragma unroll 1
    for (int L = 0; L < 3; ++L) {
        const unsigned short* wtL = wt + (size_t)L * 131072;
        float16v acc[7];
#pragma unroll
        for (int c = 0; c < 7; ++c)
#pragma unroll
            for (int e = 0; e < 16; ++e) acc[c][e] = 0.f;

        // prologue: chunk 0 fragments
        half8v wh = *(const half8v*)(wtL + jrow + kofs);
        half8v wl = *(const half8v*)(wtL + 65536 + jrow + kofs);
        half8v a[7];
#pragma unroll
        for (int c = 0; c < 7; ++c)
            a[c] = *(const half8v*)&AH[aidx32(c, l31, kofs)];

#pragma unroll
        for (int ch = 0; ch < 16; ++ch) {
            half8v nwh, nwl, na[7];
            if (ch < 15) {   // depth-1 prefetch of chunk+1 (W global + A LDS)
                const int nk = (ch + 1) * 16 + kofs;
                nwh = *(const half8v*)(wtL + jrow + nk);
                nwl = *(const half8v*)(wtL + 65536 + jrow + nk);
#pragma unroll
                for (int c = 0; c < 7; ++c)
                    na[c] = *(const half8v*)&AH[aidx32(c, l31, nk)];
            }
            __builtin_amdgcn_s_setprio(1);
#pragma unroll
            for (int c = 0; c < 7; ++c) {
                acc[c] = __builtin_amdgcn_mfma_f32_32x32x16_f16(wh, a[c], acc[c], 0, 0, 0);
                if (c < 4)   // d2 channels (4..6): hi-product only (nu-damped 100x)
                    acc[c] = __builtin_amdgcn_mfma_f32_32x32x16_f16(wl, a[c], acc[c], 0, 0, 0);
            }
            __builtin_amdgcn_s_setprio(0);
            if (ch < 15) {
                wh = nwh; wl = nwl;
#pragma unroll
                for (int c = 0; c < 7; ++c) a[c] = na[c];
            }
        }

        const float* bL = biases[L];
        __syncthreads();   // all reads of AH done before overwrite
        // D rows: j' = jb + (reg&3) + 8*(reg>>2) + 4*hh, col p = l31
#pragma unroll
        for (int q = 0; q < 4; ++q) {
            const int j0 = wv * 32 + 8 * q + 4 * hh;   // 4-aligned row base
            float bj[4];
            *(float4*)&bj[0] = *(const float4*)&bL[j0];
            float val[7][4];
#pragma unroll
            for (int r = 0; r < 4; ++r) {
                const int e = q * 4 + r;
                const float z = acc[0][e] + bj[r];
                const float t = fast_tanh(z);
                const float s = 1.f - t * t;
                val[0][r] = t;
#pragma unroll
                for (int i = 0; i < 3; ++i) {
                    const float d1 = acc[1 + i][e];
                    const float d2 = acc[4 + i][e];
                    val[1 + i][r] = s * d1;
                    val[4 + i][r] = s * d2 - 2.f * t * s * d1 * d1;
                }
            }
#pragma unroll
            for (int c = 0; c < 7; ++c) {
                const uint32_t u0 = pk2f16(val[c][0], val[c][1]);
                const uint32_t u1 = pk2f16(val[c][2], val[c][3]);
                *(uint2*)&AH[aidx32(c, l31, j0)] = make_uint2(u0, u1); // ds_write_b64
            }
        }
        __syncthreads();
    }

    // ---- layer 4: 256 -> 4, split-K across 8 waves, 16x16x32, two p-halves ----
    {
        const int l15 = lane & 15;
        const int g = lane >> 4;
        const int koct = wv * 32 + 8 * g;
        union { uint32_t u[4]; half8v v; } HB, LB;
#pragma unroll
        for (int i = 0; i < 4; ++i) {
            const float w0v = (l15 < 4) ? w4_lds[(koct + 2 * i) * 4 + l15] : 0.f;
            const float w1v = (l15 < 4) ? w4_lds[(koct + 2 * i + 1) * 4 + l15] : 0.f;
            const unsigned short h0 = f16b(w0v), h1 = f16b(w1v);
            const float r0 = w0v - (float)__builtin_bit_cast(_Float16, h0);
            const float r1 = w1v - (float)__builtin_bit_cast(_Float16, h1);
            HB.u[i] = (uint32_t)h0 | ((uint32_t)h1 << 16);
            LB.u[i] = (uint32_t)f16b(r0) | ((uint32_t)f16b(r1) << 16);
        }
        float4v acc4[6][2];
#pragma unroll
        for (int c = 0; c < 6; ++c)
#pragma unroll
            for (int ph = 0; ph < 2; ++ph) acc4[c][ph] = (float4v){0.f, 0.f, 0.f, 0.f};
#pragma unroll
        for (int c = 0; c < 6; ++c) {
#pragma unroll
            for (int ph = 0; ph < 2; ++ph) {
                const half8v ah = *(const half8v*)&AH[aidx32(1 + c, l15 + 16 * ph, koct)];
                acc4[c][ph] = __builtin_amdgcn_mfma_f32_16x16x32_f16(HB.v, ah, acc4[c][ph], 0, 0, 0);
                if (c < 3)
                    acc4[c][ph] = __builtin_amdgcn_mfma_f32_16x16x32_f16(LB.v, ah, acc4[c][ph], 0, 0, 0);
            }
        }
        if (g == 0) {   // rows 0..3 = outputs u,v,w,p for point l15 + 16*ph
#pragma unroll
            for (int c = 0; c < 6; ++c)
#pragma unroll
                for (int ph = 0; ph < 2; ++ph)
                    *(float4*)&part_lds[((wv * 6 + c) * 32 + ph * 16 + l15) * 4] =
                        make_float4(acc4[c][ph][0], acc4[c][ph][1],
                                    acc4[c][ph][2], acc4[c][ph][3]);
        }
    }
    __syncthreads();

    {          // reduce split-K partials + de-normalization scale (24 x 32 items)
        const int p = tid & 31;
#pragma unroll
        for (int co = tid >> 5; co < 24; co += 16) {
            const int o = co & 3;
            const int c6 = co >> 2;       // 0..5: 0-2 = d1_i, 3-5 = d2_i
            float sum = 0.f;
#pragma unroll
            for (int w8 = 0; w8 < 8; ++w8)
                sum += part_lds[((w8 * 6 + c6) * 32 + p) * 4 + o];
            const int i = (c6 < 3) ? c6 : (c6 - 3);
            const float xs = x_std[i];
            const float scale = y_std[o] / ((c6 < 3) ? xs : (xs * xs));
            y_lds[co * 32 + p] = sum * scale;
        }
    }
    __syncthreads();

    if (tid < 32) {           // physics loss per point
        const int p = tid;
        const float nuv = nu[0];
        #define YV(c6, o) y_lds[(((c6) * 4) + (o)) * 32 + p]
        const float cont = YV(0, 0) + YV(1, 1) + YV(2, 2);
        const float lap0 = YV(3, 0) + YV(4, 0) + YV(5, 0);
        const float lap1 = YV(3, 1) + YV(4, 1) + YV(5, 1);
        const float lap2 = YV(3, 2) + YV(4, 2) + YV(5, 2);
        const float mx = YV(0, 3) - nuv * lap0;
        const float my = YV(1, 3) - nuv * lap1;
        const float mz = YV(2, 3) - nuv * lap2;
        out[base_pt + p] = cont * cont + mx * mx + my * my + mz * mz;
        #undef YV
    }
}

extern "C" void kernel_launch(void* const* d_in, const int* in_sizes, int n_in,
                              void* d_out, int out_size, void* d_ws, size_t ws_size,
                              hipStream_t stream)
{
    const float* x_norm = (const float*)d_in[0];
    const float* nu     = (const float*)d_in[1];
    const float* x_std  = (const float*)d_in[2];
    const float* y_std  = (const float*)d_in[3];
    const float* W0 = (const float*)d_in[4];  const float* b0 = (const float*)d_in[5];
    const float* W1 = (const float*)d_in[6];  const float* b1 = (const float*)d_in[7];
    const float* W2 = (const float*)d_in[8];  const float* b2 = (const float*)d_in[9];
    const float* W3 = (const float*)d_in[10]; const float* b3 = (const float*)d_in[11];
    const float* W4 = (const float*)d_in[12];
    (void)n_in; (void)out_size; (void)ws_size;
    unsigned short* wt = (unsigned short*)d_ws;   // 786432 B
    float* out = (float*)d_out;
    const int npts = in_sizes[0] / 3;

    wt_split_kernel<<<48, 256, 0, stream>>>(W1, W2, W3, wt);
    pinn_mfma<<<npts / NPTS_WG, 512, 0, stream>>>(x_norm, nu, x_std, y_std,
        W0, b0, b1, b2, b3, W4, wt, out);
}